// Round 1
// baseline (1827.260 us; speedup 1.0000x reference)
//
#include <hip/hip_runtime.h>

#define NPROT 20000
#define NDRUG 4000
#define INDRUG 4000
#define NET 128
#define NBASE 32
#define NEMBED 48
#define PDDIM 16
#define H1C 32
#define H2C 16
#define RGCNIN 64
#define EPP 800000
#define EDP 400000
#define EDD 1000000

// ---------------- workspace layout (float offsets) ----------------
#define O_CNTPP   0          // 20000 int
#define O_DIS     20000      // 20000 f
#define O_H1      40000      // 640000 f
#define O_AGG1    680000     // 640000 f
#define O_H2      1320000    // 320000 f
#define O_AGG2    1640000    // 320000 f
#define O_DPSUM   1960000    // 64000 f
#define O_DPCNT   2024000    // 4000 int
#define O_XD      2028000    // 256000 f  [4000][64]
#define O_WET1    2284000    // 262144 f  [128][64][32]
#define O_WET2    2546144    // 65536 f   [128][32][16]
#define O_CNTDD   2611680    // 4000 int
#define O_RSUM1   2615680    // 128000 f
#define O_XD1     2743680    // 128000 f
#define O_RSUM2   2871680    // 64000 f
// total ~2.94M floats = 11.8 MB

__global__ void k_count_int(const int* __restrict__ dst, int ne, int* __restrict__ cnt){
  int i = blockIdx.x*256 + threadIdx.x;
  if(i < ne) atomicAdd(&cnt[dst[i]], 1);
}

__global__ void k_dis(const int* __restrict__ cnt, float* __restrict__ dis, int n){
  int i = blockIdx.x*256 + threadIdx.x;
  if(i < n) dis[i] = rsqrtf((float)cnt[i] + 1.0f);
}

template<int K, int NC, bool RELU_IN>
__global__ void k_gemm(const float* __restrict__ A, const float* __restrict__ W,
                       float* __restrict__ C, int M){
  __shared__ float Ws[K*NC];
  for(int i = threadIdx.x; i < K*NC; i += 256) Ws[i] = W[i];
  __syncthreads();
  int idx = blockIdx.x*256 + threadIdx.x;
  int row = idx / NC, col = idx % NC;
  if(row >= M) return;
  const float* a = A + row*K;
  float acc = 0.f;
  #pragma unroll
  for(int k = 0; k < K; k++){
    float v = a[k];
    if(RELU_IN) v = fmaxf(v, 0.f);
    acc = fmaf(v, Ws[k*NC + col], acc);
  }
  C[idx] = acc;
}

template<int NC>
__global__ void k_gcn_init(const float* __restrict__ h, const float* __restrict__ dis,
                           const float* __restrict__ b, float* __restrict__ agg, int n){
  int i = blockIdx.x*256 + threadIdx.x;
  if(i < n*NC){
    int r = i / NC, c = i % NC;
    float d = dis[r];
    agg[i] = fmaf(h[i], d*d, b[c]);
  }
}

template<int NC>
__global__ void k_gcn_scatter(const float* __restrict__ h, const float* __restrict__ dis,
                              const int* __restrict__ src, const int* __restrict__ dst,
                              int ne, float* __restrict__ agg){
  int gid = blockIdx.x*256 + threadIdx.x;
  int e = gid / NC, j = gid % NC;
  if(e >= ne) return;
  int s = src[e], d = dst[e];
  atomicAdd(&agg[d*NC + j], h[s*NC + j] * dis[s] * dis[d]);
}

__global__ void k_dp_scatter(const float* __restrict__ xp2, const int* __restrict__ src,
                             const int* __restrict__ dst, float* __restrict__ dpsum,
                             int* __restrict__ dpcnt){
  int gid = blockIdx.x*256 + threadIdx.x;
  int e = gid >> 4, j = gid & 15;
  if(e >= EDP) return;
  int s = src[e], d = dst[e] - NPROT;
  atomicAdd(&dpsum[d*16 + j], xp2[s*16 + j]);
  if(j == 0) atomicAdd(&dpcnt[d], 1);
}

__global__ void k_hier(const float* __restrict__ dpsum, const int* __restrict__ dpcnt,
                       const float* __restrict__ hg, float* __restrict__ xd){
  int gid = blockIdx.x*256 + threadIdx.x;
  int d = gid >> 4, j = gid & 15;
  if(d >= NDRUG) return;
  float inv = 1.0f / fmaxf((float)dpcnt[d], 1.0f);
  float acc = 0.f;
  #pragma unroll
  for(int k = 0; k < 16; k++) acc = fmaf(dpsum[d*16 + k] * inv, hg[k*16 + j], acc);
  xd[d*64 + 48 + j] = acc;
}

// xd[:, 0:48] += x_drug @ embed (k-split across grid.y, atomic combine)
__global__ void k_embed(const float* __restrict__ xdrug, const float* __restrict__ embed,
                        float* __restrict__ xd){
  __shared__ float xs[64][65];
  __shared__ float es[64][48];
  int tid = threadIdx.x;
  int r = tid & 63;         // row within tile
  int cg = tid >> 6;        // 0..3 -> cols cg*12 .. cg*12+11
  int row0 = blockIdx.x * 64;
  int k0c = blockIdx.y * 512;
  float acc[12];
  #pragma unroll
  for(int j = 0; j < 12; j++) acc[j] = 0.f;

  for(int kt = 0; kt < 512; kt += 64){
    int k0 = k0c + kt;
    if(k0 >= INDRUG) break;
    __syncthreads();
    // stage x tile: 64 rows x 64 k (float4 global loads, scalar LDS stores for pad-65)
    #pragma unroll
    for(int i = 0; i < 4; i++){
      int lin = tid + i*256;     // 0..1023 float4 slots
      int rr = lin >> 4;         // 0..63
      int kc = lin & 15;         // float4 index within row
      int grow = row0 + rr;
      int gk = k0 + kc*4;
      float4 v = make_float4(0.f,0.f,0.f,0.f);
      if(grow < NDRUG && gk + 3 < INDRUG)
        v = *(const float4*)&xdrug[(size_t)grow * INDRUG + gk];
      xs[rr][kc*4+0] = v.x; xs[rr][kc*4+1] = v.y; xs[rr][kc*4+2] = v.z; xs[rr][kc*4+3] = v.w;
    }
    // stage embed tile: 64 k x 48 cols
    #pragma unroll
    for(int i = 0; i < 3; i++){
      int lin = tid + i*256;     // 0..767 float4 slots
      int kk = lin / 12;
      int jc = lin % 12;
      float4 v = make_float4(0.f,0.f,0.f,0.f);
      if(k0 + kk < INDRUG)
        v = *(const float4*)&embed[(size_t)(k0 + kk) * NEMBED + jc*4];
      *(float4*)&es[kk][jc*4] = v;
    }
    __syncthreads();
    #pragma unroll 8
    for(int kk = 0; kk < 64; kk++){
      float xv = xs[r][kk];
      const float4* ep = (const float4*)&es[kk][cg*12];
      float4 e0 = ep[0], e1 = ep[1], e2 = ep[2];
      acc[0]  = fmaf(xv, e0.x, acc[0]);  acc[1]  = fmaf(xv, e0.y, acc[1]);
      acc[2]  = fmaf(xv, e0.z, acc[2]);  acc[3]  = fmaf(xv, e0.w, acc[3]);
      acc[4]  = fmaf(xv, e1.x, acc[4]);  acc[5]  = fmaf(xv, e1.y, acc[5]);
      acc[6]  = fmaf(xv, e1.z, acc[6]);  acc[7]  = fmaf(xv, e1.w, acc[7]);
      acc[8]  = fmaf(xv, e2.x, acc[8]);  acc[9]  = fmaf(xv, e2.y, acc[9]);
      acc[10] = fmaf(xv, e2.z, acc[10]); acc[11] = fmaf(xv, e2.w, acc[11]);
    }
  }
  int grow = row0 + r;
  if(grow < NDRUG){
    #pragma unroll
    for(int j = 0; j < 12; j++)
      atomicAdd(&xd[grow*64 + cg*12 + j], acc[j]);
  }
}

__global__ void k_embed_fin(float* __restrict__ xd, const float* __restrict__ dnorm){
  int gid = blockIdx.x*256 + threadIdx.x;
  if(gid >= NDRUG*48) return;
  int d = gid / 48, j = gid % 48;
  xd[d*64 + j] = xd[d*64 + j] / dnorm[d];
}

// W_et[et][i][j] = sum_b att[et][b] * basis[b][i][j]
__global__ void k_wet(const float* __restrict__ att, const float* __restrict__ basis,
                      float* __restrict__ wet, int inout){
  int gid = blockIdx.x*256 + threadIdx.x;
  if(gid >= NET * inout) return;
  int et = gid / inout, ij = gid % inout;
  float acc = 0.f;
  #pragma unroll
  for(int b = 0; b < NBASE; b++)
    acc = fmaf(att[et*NBASE + b], basis[b*inout + ij], acc);
  wet[gid] = acc;
}

// RGCN layer 1: per edge, msg = xd[src](64) @ wet1[et](64x32) -> atomic into rsum1[dst]
__global__ void k_rgcn1(const float* __restrict__ xd, const int* __restrict__ src,
                        const int* __restrict__ dst, const int* __restrict__ et,
                        const float* __restrict__ wet, float* __restrict__ rsum){
  int tid = threadIdx.x;
  int e = blockIdx.x*64 + (tid >> 2);
  if(e >= EDD) return;
  int jg = tid & 3;                       // 8 cols each
  int s = src[e], d = dst[e], t = et[e];
  const float* x = xd + s*64;
  const float* w = wet + t*2048 + jg*8;
  float acc[8] = {0,0,0,0,0,0,0,0};
  #pragma unroll 8
  for(int i = 0; i < 64; i++){
    float xv = x[i];
    const float4* wp = (const float4*)(w + i*32);
    float4 w0 = wp[0], w1 = wp[1];
    acc[0]=fmaf(xv,w0.x,acc[0]); acc[1]=fmaf(xv,w0.y,acc[1]);
    acc[2]=fmaf(xv,w0.z,acc[2]); acc[3]=fmaf(xv,w0.w,acc[3]);
    acc[4]=fmaf(xv,w1.x,acc[4]); acc[5]=fmaf(xv,w1.y,acc[5]);
    acc[6]=fmaf(xv,w1.z,acc[6]); acc[7]=fmaf(xv,w1.w,acc[7]);
  }
  float* out = rsum + d*32 + jg*8;
  #pragma unroll
  for(int j = 0; j < 8; j++) atomicAdd(&out[j], acc[j]);
}

// RGCN layer 2: per edge, msg = xd1[src](32) @ wet2[et](32x16)
__global__ void k_rgcn2(const float* __restrict__ xd1, const int* __restrict__ src,
                        const int* __restrict__ dst, const int* __restrict__ et,
                        const float* __restrict__ wet, float* __restrict__ rsum){
  int tid = threadIdx.x;
  int e = blockIdx.x*128 + (tid >> 1);
  if(e >= EDD) return;
  int jg = tid & 1;                       // 8 cols each
  int s = src[e], d = dst[e], t = et[e];
  const float* x = xd1 + s*32;
  const float* w = wet + t*512 + jg*8;
  float acc[8] = {0,0,0,0,0,0,0,0};
  #pragma unroll 8
  for(int i = 0; i < 32; i++){
    float xv = x[i];
    const float4* wp = (const float4*)(w + i*16);
    float4 w0 = wp[0], w1 = wp[1];
    acc[0]=fmaf(xv,w0.x,acc[0]); acc[1]=fmaf(xv,w0.y,acc[1]);
    acc[2]=fmaf(xv,w0.z,acc[2]); acc[3]=fmaf(xv,w0.w,acc[3]);
    acc[4]=fmaf(xv,w1.x,acc[4]); acc[5]=fmaf(xv,w1.y,acc[5]);
    acc[6]=fmaf(xv,w1.z,acc[6]); acc[7]=fmaf(xv,w1.w,acc[7]);
  }
  float* out = rsum + d*16 + jg*8;
  #pragma unroll
  for(int j = 0; j < 8; j++) atomicAdd(&out[j], acc[j]);
}

__global__ void k_root1(const float* __restrict__ rsum, const int* __restrict__ cnt,
                        const float* __restrict__ xd, const float* __restrict__ root,
                        float* __restrict__ xd1){
  int gid = blockIdx.x*256 + threadIdx.x;
  int d = gid >> 5, j = gid & 31;
  if(d >= NDRUG) return;
  float inv = 1.0f / fmaxf((float)cnt[d], 1.0f);
  float acc = rsum[d*32 + j] * inv;
  #pragma unroll
  for(int i = 0; i < 64; i++) acc = fmaf(xd[d*64 + i], root[i*32 + j], acc);
  xd1[d*32 + j] = fmaxf(acc, 0.f);
}

__global__ void k_root2(const float* __restrict__ rsum, const int* __restrict__ cnt,
                        const float* __restrict__ xd1, const float* __restrict__ root,
                        float* __restrict__ out){
  int gid = blockIdx.x*256 + threadIdx.x;
  int d = gid >> 4, j = gid & 15;
  if(d >= NDRUG) return;
  float inv = 1.0f / fmaxf((float)cnt[d], 1.0f);
  float acc = rsum[d*16 + j] * inv;
  #pragma unroll
  for(int i = 0; i < 32; i++) acc = fmaf(xd1[d*32 + i], root[i*16 + j], acc);
  out[d*16 + j] = acc;
}

extern "C" void kernel_launch(void* const* d_in, const int* in_sizes, int n_in,
                              void* d_out, int out_size, void* d_ws, size_t ws_size,
                              hipStream_t stream){
  const float* x_drug  = (const float*)d_in[0];
  const float* d_norm  = (const float*)d_in[1];
  const float* x_prot  = (const float*)d_in[2];
  const int*   pp_ei   = (const int*)d_in[3];
  const int*   dp_ei   = (const int*)d_in[4];
  const int*   dd_ei   = (const int*)d_in[6];
  const int*   dd_et   = (const int*)d_in[7];
  const float* embed   = (const float*)d_in[9];
  const float* W1      = (const float*)d_in[10];
  const float* b1      = (const float*)d_in[11];
  const float* W2      = (const float*)d_in[12];
  const float* b2      = (const float*)d_in[13];
  const float* hgw     = (const float*)d_in[14];
  const float* att1    = (const float*)d_in[15];
  const float* basis1  = (const float*)d_in[16];
  const float* root1   = (const float*)d_in[17];
  const float* att2    = (const float*)d_in[18];
  const float* basis2  = (const float*)d_in[19];
  const float* root2   = (const float*)d_in[20];
  float* out = (float*)d_out;

  float* ws = (float*)d_ws;
  int*   cnt_pp = (int*)(ws + O_CNTPP);
  float* dis    = ws + O_DIS;
  float* h1     = ws + O_H1;
  float* agg1   = ws + O_AGG1;
  float* h2     = ws + O_H2;
  float* agg2   = ws + O_AGG2;
  float* dpsum  = ws + O_DPSUM;
  int*   dpcnt  = (int*)(ws + O_DPCNT);
  float* xd     = ws + O_XD;
  float* wet1   = ws + O_WET1;
  float* wet2   = ws + O_WET2;
  int*   cntdd  = (int*)(ws + O_CNTDD);
  float* rsum1  = ws + O_RSUM1;
  float* xd1    = ws + O_XD1;
  float* rsum2  = ws + O_RSUM2;

  const int* pp_src = pp_ei;
  const int* pp_dst = pp_ei + EPP;
  const int* dp_src = dp_ei;
  const int* dp_dst = dp_ei + EDP;
  const int* dd_src = dd_ei;
  const int* dd_dst = dd_ei + EDD;

  // zero accumulators
  hipMemsetAsync(cnt_pp, 0, NPROT*sizeof(int), stream);
  hipMemsetAsync(dpsum,  0, (64000 + 4000)*sizeof(float), stream);  // dpsum + dpcnt
  hipMemsetAsync(xd,     0, NDRUG*64*sizeof(float), stream);
  hipMemsetAsync(cntdd,  0, NDRUG*sizeof(int), stream);
  hipMemsetAsync(rsum1,  0, NDRUG*32*sizeof(float), stream);
  hipMemsetAsync(rsum2,  0, NDRUG*16*sizeof(float), stream);

  // ---- PP GCN layer 1 ----
  k_count_int<<<(EPP+255)/256, 256, 0, stream>>>(pp_dst, EPP, cnt_pp);
  k_dis<<<(NPROT+255)/256, 256, 0, stream>>>(cnt_pp, dis, NPROT);
  k_gemm<64,32,false><<<(NPROT*32+255)/256, 256, 0, stream>>>(x_prot, W1, h1, NPROT);
  k_gcn_init<32><<<(NPROT*32+255)/256, 256, 0, stream>>>(h1, dis, b1, agg1, NPROT);
  k_gcn_scatter<32><<<(EPP*32)/256, 256, 0, stream>>>(h1, dis, pp_src, pp_dst, EPP, agg1);
  // ---- PP GCN layer 2 (relu on input) ----
  k_gemm<32,16,true><<<(NPROT*16+255)/256, 256, 0, stream>>>(agg1, W2, h2, NPROT);
  k_gcn_init<16><<<(NPROT*16+255)/256, 256, 0, stream>>>(h2, dis, b2, agg2, NPROT);
  k_gcn_scatter<16><<<(EPP*16)/256, 256, 0, stream>>>(h2, dis, pp_src, pp_dst, EPP, agg2);
  // ---- hierarchy conv prot->drug ----
  k_dp_scatter<<<(EDP*16)/256, 256, 0, stream>>>(agg2, dp_src, dp_dst, dpsum, dpcnt);
  k_hier<<<(NDRUG*16+255)/256, 256, 0, stream>>>(dpsum, dpcnt, hgw, xd);
  // ---- drug embedding ----
  {
    dim3 g((NDRUG+63)/64, 8);
    k_embed<<<g, 256, 0, stream>>>(x_drug, embed, xd);
  }
  k_embed_fin<<<(NDRUG*48+255)/256, 256, 0, stream>>>(xd, d_norm);
  // ---- RGCN prep ----
  k_wet<<<(NET*2048+255)/256, 256, 0, stream>>>(att1, basis1, wet1, 2048);
  k_wet<<<(NET*512+255)/256, 256, 0, stream>>>(att2, basis2, wet2, 512);
  k_count_int<<<(EDD+255)/256, 256, 0, stream>>>(dd_dst, EDD, cntdd);
  // ---- RGCN layer 1 ----
  k_rgcn1<<<EDD/64, 256, 0, stream>>>(xd, dd_src, dd_dst, dd_et, wet1, rsum1);
  k_root1<<<(NDRUG*32+255)/256, 256, 0, stream>>>(rsum1, cntdd, xd, root1, xd1);
  // ---- RGCN layer 2 ----
  k_rgcn2<<<(EDD+127)/128, 256, 0, stream>>>(xd1, dd_src, dd_dst, dd_et, wet2, rsum2);
  k_root2<<<(NDRUG*16+255)/256, 256, 0, stream>>>(rsum2, cntdd, xd1, root2, out);
}

// Round 3
// 691.318 us; speedup vs baseline: 2.6432x; 2.6432x over previous
//
#include <hip/hip_runtime.h>

#define NPROT 20000
#define NDRUG 4000
#define INDRUG 4000
#define NET 128
#define NBASE 32
#define NEMBED 48
#define PDDIM 16
#define H1C 32
#define H2C 16
#define RGCNIN 64
#define EPP 800000
#define EDP 400000
#define EDD 1000000
#define NBLK 64

__device__ __forceinline__ void fma4(float4& a, float s, const float4& b){
  a.x = fmaf(s, b.x, a.x); a.y = fmaf(s, b.y, a.y);
  a.z = fmaf(s, b.z, a.z); a.w = fmaf(s, b.w, a.w);
}

// ======================= shared kernels =======================

template<int K, int NC, bool RELU_IN>
__global__ void k_gemm(const float* __restrict__ A, const float* __restrict__ W,
                       float* __restrict__ C, int M){
  __shared__ float Ws[K*NC];
  for(int i = threadIdx.x; i < K*NC; i += 256) Ws[i] = W[i];
  __syncthreads();
  int idx = blockIdx.x*256 + threadIdx.x;
  int row = idx / NC, col = idx % NC;
  if(row >= M) return;
  const float* a = A + row*K;
  float acc = 0.f;
  #pragma unroll
  for(int k = 0; k < K; k++){
    float v = a[k];
    if(RELU_IN) v = fmaxf(v, 0.f);
    acc = fmaf(v, Ws[k*NC + col], acc);
  }
  C[idx] = acc;
}

__global__ void k_wet(const float* __restrict__ att, const float* __restrict__ basis,
                      float* __restrict__ wet, int inout){
  int gid = blockIdx.x*256 + threadIdx.x;
  if(gid >= NET * inout) return;
  int et = gid / inout, ij = gid % inout;
  float acc = 0.f;
  #pragma unroll
  for(int b = 0; b < NBASE; b++)
    acc = fmaf(att[et*NBASE + b], basis[b*inout + ij], acc);
  wet[gid] = acc;
}

// ======================= fast path: CSR build =======================

template<int PB>
__global__ void k_hist(const int* __restrict__ dst, int ne, int sub, int b0,
                       int* __restrict__ gh, int bins){
  __shared__ int h[PB];
  for(int i = threadIdx.x; i < PB; i += 256) h[i] = 0;
  __syncthreads();
  int chunk = (ne + NBLK - 1) / NBLK;
  int s0 = blockIdx.x*chunk, s1 = min(s0 + chunk, ne);
  for(int i = s0 + threadIdx.x; i < s1; i += 256){
    int b = dst[i] - sub - b0;
    if(b >= 0 && b < PB) atomicAdd(&h[b], 1);
  }
  __syncthreads();
  for(int i = threadIdx.x; i < PB; i += 256) gh[blockIdx.x*bins + b0 + i] = h[i];
}

__global__ void k_scan_bins(int* __restrict__ gh, int* __restrict__ cnt, int bins){
  int bin = blockIdx.x*256 + threadIdx.x;
  if(bin >= bins) return;
  int run = 0;
  for(int b = 0; b < NBLK; b++){
    int v = gh[b*bins + bin];
    gh[b*bins + bin] = run;
    run += v;
  }
  cnt[bin] = run;
}

__global__ void k_scan_off(const int* __restrict__ cnt, int* __restrict__ off, int bins){
  __shared__ int ps[1024];
  int t = threadIdx.x;
  int C = (bins + 1023) >> 10;
  int lo = t*C, hi = min(lo + C, bins);
  int s = 0;
  for(int i = lo; i < hi; i++) s += cnt[i];
  ps[t] = s;
  __syncthreads();
  for(int d = 1; d < 1024; d <<= 1){
    int v = (t >= d) ? ps[t-d] : 0;
    __syncthreads();
    ps[t] += v;
    __syncthreads();
  }
  int run = ps[t] - s;   // exclusive
  for(int i = lo; i < hi; i++){ off[i] = run; run += cnt[i]; }
  if(t == 1023) off[bins] = ps[1023];
}

// MODE 0: outp[pos] = src[e]   MODE 1: outp[e] = pos
template<int PB, int MODE>
__global__ void k_scatter(const int* __restrict__ dst, const int* __restrict__ src,
                          int ne, int sub, int b0, const int* __restrict__ gh,
                          const int* __restrict__ off, int bins, int* __restrict__ outp){
  __shared__ int h[PB];
  for(int i = threadIdx.x; i < PB; i += 256)
    h[i] = off[b0 + i] + gh[blockIdx.x*bins + b0 + i];
  __syncthreads();
  int chunk = (ne + NBLK - 1) / NBLK;
  int s0 = blockIdx.x*chunk, s1 = min(s0 + chunk, ne);
  for(int i = s0 + threadIdx.x; i < s1; i += 256){
    int b = dst[i] - sub - b0;
    if(b >= 0 && b < PB){
      int p = atomicAdd(&h[b], 1);
      if(MODE == 0) outp[p] = src[i];
      else          outp[i] = p;
    }
  }
}

__global__ void k_dis_off(const int* __restrict__ off, float* __restrict__ dis, int n){
  int i = blockIdx.x*256 + threadIdx.x;
  if(i < n) dis[i] = rsqrtf((float)(off[i+1] - off[i]) + 1.0f);
}

// ======================= fast path: gathers =======================

template<int NC>
__global__ void k_gcn_gather(const float* __restrict__ h, const float* __restrict__ dis,
                             const int* __restrict__ off, const int* __restrict__ srcperm,
                             const float* __restrict__ b, float* __restrict__ agg, int n){
  int wv = threadIdx.x >> 6, lane = threadIdx.x & 63;
  int d = blockIdx.x*4 + wv;
  if(d >= n) return;
  int col = lane & (NC-1), g = lane / NC;
  int o0 = off[d], cnt = off[d+1] - o0;
  float s = 0.f;
  for(int i = g; i < cnt; i += 64/NC){
    int sidx = srcperm[o0 + i];
    s = fmaf(h[sidx*NC + col], dis[sidx], s);
  }
  if(NC <= 32) s += __shfl_xor(s, 32);
  if(NC <= 16) s += __shfl_xor(s, 16);
  if(g == 0){
    float dd = dis[d];
    agg[d*NC + col] = s*dd + h[d*NC + col]*dd*dd + b[col];
  }
}

__global__ void k_dp_gather(const float* __restrict__ xp2, const int* __restrict__ off,
                            const int* __restrict__ srcperm, const float* __restrict__ hg,
                            float* __restrict__ xd){
  int wv = threadIdx.x >> 6, lane = threadIdx.x & 63;
  int d = blockIdx.x*4 + wv;
  if(d >= NDRUG) return;
  int col = lane & 15, g = lane >> 4;
  int o0 = off[d], cnt = off[d+1] - o0;
  float s = 0.f;
  for(int i = g; i < cnt; i += 4) s += xp2[srcperm[o0 + i]*16 + col];
  s += __shfl_xor(s, 16);
  s += __shfl_xor(s, 32);
  s = s / fmaxf((float)cnt, 1.0f);
  float acc = 0.f;
  #pragma unroll
  for(int k = 0; k < 16; k++){
    float v = __shfl(s, k);
    acc = fmaf(v, hg[k*16 + col], acc);
  }
  if(g == 0) xd[d*64 + 48 + col] = acc;
}

// ======================= fast path: embed GEMM (partials) =======================

__global__ void k_embed_p(const float* __restrict__ xdrug, const float* __restrict__ embed,
                          float* __restrict__ xdp){
  __shared__ float xs[64][65];
  __shared__ float es[64][48];
  int tid = threadIdx.x;
  int r = tid & 63;
  int cg = tid >> 6;
  int row0 = blockIdx.x * 64;
  int k0c = blockIdx.y * 512;
  float acc[12];
  #pragma unroll
  for(int j = 0; j < 12; j++) acc[j] = 0.f;

  for(int kt = 0; kt < 512; kt += 64){
    int k0 = k0c + kt;
    if(k0 >= INDRUG) break;
    __syncthreads();
    #pragma unroll
    for(int i = 0; i < 4; i++){
      int lin = tid + i*256;
      int rr = lin >> 4, kc = lin & 15;
      int grow = row0 + rr, gk = k0 + kc*4;
      float4 v = make_float4(0.f,0.f,0.f,0.f);
      if(grow < NDRUG && gk + 3 < INDRUG)
        v = *(const float4*)&xdrug[(size_t)grow * INDRUG + gk];
      xs[rr][kc*4+0]=v.x; xs[rr][kc*4+1]=v.y; xs[rr][kc*4+2]=v.z; xs[rr][kc*4+3]=v.w;
    }
    #pragma unroll
    for(int i = 0; i < 3; i++){
      int lin = tid + i*256;
      int kk = lin / 12, jc = lin % 12;
      float4 v = make_float4(0.f,0.f,0.f,0.f);
      if(k0 + kk < INDRUG)
        v = *(const float4*)&embed[(size_t)(k0 + kk) * NEMBED + jc*4];
      *(float4*)&es[kk][jc*4] = v;
    }
    __syncthreads();
    #pragma unroll 8
    for(int kk = 0; kk < 64; kk++){
      float xv = xs[r][kk];
      const float4* ep = (const float4*)&es[kk][cg*12];
      float4 e0 = ep[0], e1 = ep[1], e2 = ep[2];
      acc[0]=fmaf(xv,e0.x,acc[0]);  acc[1]=fmaf(xv,e0.y,acc[1]);
      acc[2]=fmaf(xv,e0.z,acc[2]);  acc[3]=fmaf(xv,e0.w,acc[3]);
      acc[4]=fmaf(xv,e1.x,acc[4]);  acc[5]=fmaf(xv,e1.y,acc[5]);
      acc[6]=fmaf(xv,e1.z,acc[6]);  acc[7]=fmaf(xv,e1.w,acc[7]);
      acc[8]=fmaf(xv,e2.x,acc[8]);  acc[9]=fmaf(xv,e2.y,acc[9]);
      acc[10]=fmaf(xv,e2.z,acc[10]); acc[11]=fmaf(xv,e2.w,acc[11]);
    }
  }
  int grow = row0 + r;
  if(grow < NDRUG){
    float* op = xdp + ((size_t)blockIdx.y*NDRUG + grow)*48 + cg*12;
    *(float4*)(op+0) = make_float4(acc[0],acc[1],acc[2],acc[3]);
    *(float4*)(op+4) = make_float4(acc[4],acc[5],acc[6],acc[7]);
    *(float4*)(op+8) = make_float4(acc[8],acc[9],acc[10],acc[11]);
  }
}

__global__ void k_embed_fin2(const float* __restrict__ xdp, const float* __restrict__ dnorm,
                             float* __restrict__ xd){
  int gid = blockIdx.x*256 + threadIdx.x;
  if(gid >= NDRUG*48) return;
  int d = gid / 48, j = gid % 48;
  float s = 0.f;
  #pragma unroll
  for(int y = 0; y < 8; y++) s += xdp[(size_t)y*NDRUG*48 + gid];
  xd[d*64 + j] = s / dnorm[d];
}

// ======================= fast path: RGCN msgs + reduce =======================

__global__ __launch_bounds__(256) void k_rgcn1_msgs(
    const float* __restrict__ xd, const int* __restrict__ src,
    const int* __restrict__ et, const int* __restrict__ pos,
    const float* __restrict__ wet, float* __restrict__ msgs){
  int tid = threadIdx.x;
  int wv = tid >> 6, lane = tid & 63;
  int g = lane >> 3, c4 = (lane & 7) << 2;
  int e0 = (blockIdx.x*4 + wv)*16 + g*2;
  if(e0 + 1 >= EDD) return;
  int sA = src[e0], sB = src[e0+1];
  int tA = et[e0],  tB = et[e0+1];
  int pA = pos[e0], pB = pos[e0+1];
  float4 accA = make_float4(0,0,0,0), accB = make_float4(0,0,0,0);
  const float* xa = xd + sA*64;
  const float* xb = xd + sB*64;
  if(tA == tB){
    const float* W = wet + tA*2048 + c4;
    #pragma unroll 4
    for(int i = 0; i < 64; i += 4){
      float4 xA = *(const float4*)(xa + i);
      float4 xB = *(const float4*)(xb + i);
      float4 w0 = *(const float4*)(W + (i+0)*32);
      float4 w1 = *(const float4*)(W + (i+1)*32);
      float4 w2 = *(const float4*)(W + (i+2)*32);
      float4 w3 = *(const float4*)(W + (i+3)*32);
      fma4(accA, xA.x, w0); fma4(accA, xA.y, w1); fma4(accA, xA.z, w2); fma4(accA, xA.w, w3);
      fma4(accB, xB.x, w0); fma4(accB, xB.y, w1); fma4(accB, xB.z, w2); fma4(accB, xB.w, w3);
    }
  } else {
    const float* WA = wet + tA*2048 + c4;
    const float* WB = wet + tB*2048 + c4;
    #pragma unroll 4
    for(int i = 0; i < 64; i++){
      float a = xa[i], b = xb[i];
      float4 wA = *(const float4*)(WA + i*32);
      float4 wB = *(const float4*)(WB + i*32);
      fma4(accA, a, wA); fma4(accB, b, wB);
    }
  }
  *(float4*)(msgs + (size_t)pA*32 + c4) = accA;
  *(float4*)(msgs + (size_t)pB*32 + c4) = accB;
}

__global__ __launch_bounds__(256) void k_rgcn2_msgs(
    const float* __restrict__ xd1, const int* __restrict__ src,
    const int* __restrict__ et, const int* __restrict__ pos,
    const float* __restrict__ wet, float* __restrict__ msgs){
  int tid = threadIdx.x;
  int wv = tid >> 6, lane = tid & 63;
  int g = lane >> 2, c4 = (lane & 3) << 2;
  int e0 = (blockIdx.x*4 + wv)*32 + g*2;
  if(e0 + 1 >= EDD) return;
  int sA = src[e0], sB = src[e0+1];
  int tA = et[e0],  tB = et[e0+1];
  int pA = pos[e0], pB = pos[e0+1];
  float4 accA = make_float4(0,0,0,0), accB = make_float4(0,0,0,0);
  const float* xa = xd1 + sA*32;
  const float* xb = xd1 + sB*32;
  if(tA == tB){
    const float* W = wet + tA*512 + c4;
    #pragma unroll
    for(int i = 0; i < 32; i += 4){
      float4 xA = *(const float4*)(xa + i);
      float4 xB = *(const float4*)(xb + i);
      float4 w0 = *(const float4*)(W + (i+0)*16);
      float4 w1 = *(const float4*)(W + (i+1)*16);
      float4 w2 = *(const float4*)(W + (i+2)*16);
      float4 w3 = *(const float4*)(W + (i+3)*16);
      fma4(accA, xA.x, w0); fma4(accA, xA.y, w1); fma4(accA, xA.z, w2); fma4(accA, xA.w, w3);
      fma4(accB, xB.x, w0); fma4(accB, xB.y, w1); fma4(accB, xB.z, w2); fma4(accB, xB.w, w3);
    }
  } else {
    const float* WA = wet + tA*512 + c4;
    const float* WB = wet + tB*512 + c4;
    #pragma unroll 4
    for(int i = 0; i < 32; i++){
      float a = xa[i], b = xb[i];
      float4 wA = *(const float4*)(WA + i*16);
      float4 wB = *(const float4*)(WB + i*16);
      fma4(accA, a, wA); fma4(accB, b, wB);
    }
  }
  *(float4*)(msgs + (size_t)pA*16 + c4) = accA;
  *(float4*)(msgs + (size_t)pB*16 + c4) = accB;
}

__global__ void k_rgcn1_reduce(const float* __restrict__ msgs, const int* __restrict__ off,
                               const float* __restrict__ xd, const float* __restrict__ root,
                               float* __restrict__ xd1){
  int wv = threadIdx.x >> 6, lane = threadIdx.x & 63;
  int d = blockIdx.x*4 + wv;
  if(d >= NDRUG) return;
  int col = lane & 31, g = lane >> 5;
  int o0 = off[d], cnt = off[d+1] - o0;
  float s = 0.f;
  for(int i = g; i < cnt; i += 2) s += msgs[(size_t)(o0 + i)*32 + col];
  s += __shfl_xor(s, 32);
  float r = 0.f;
  const float* x = xd + d*64;
  #pragma unroll 8
  for(int i = 0; i < 64; i++) r = fmaf(x[i], root[i*32 + col], r);
  if(g == 0){
    float v = s / fmaxf((float)cnt, 1.0f) + r;
    xd1[d*32 + col] = fmaxf(v, 0.f);
  }
}

__global__ void k_rgcn2_reduce(const float* __restrict__ msgs, const int* __restrict__ off,
                               const float* __restrict__ xd1, const float* __restrict__ root,
                               float* __restrict__ out){
  int wv = threadIdx.x >> 6, lane = threadIdx.x & 63;
  int d = blockIdx.x*4 + wv;
  if(d >= NDRUG) return;
  int col = lane & 15, g = lane >> 4;
  int o0 = off[d], cnt = off[d+1] - o0;
  float s = 0.f;
  for(int i = g; i < cnt; i += 4) s += msgs[(size_t)(o0 + i)*16 + col];
  s += __shfl_xor(s, 16);
  s += __shfl_xor(s, 32);
  float r = 0.f;
  const float* x = xd1 + d*32;
  #pragma unroll 8
  for(int i = 0; i < 32; i++) r = fmaf(x[i], root[i*16 + col], r);
  if(g == 0) out[d*16 + col] = s / fmaxf((float)cnt, 1.0f) + r;
}

// ======================= fallback (round-1) kernels =======================

#define O_CNTPP   0
#define O_DIS     20000
#define O_H1      40000
#define O_AGG1    680000
#define O_H2      1320000
#define O_AGG2    1640000
#define O_DPSUM   1960000
#define O_DPCNT   2024000
#define O_XD      2028000
#define O_WET1    2284000
#define O_WET2    2546144
#define O_CNTDD   2611680
#define O_RSUM1   2615680
#define O_XD1     2743680
#define O_RSUM2   2871680

__global__ void k_count_int(const int* __restrict__ dst, int ne, int* __restrict__ cnt){
  int i = blockIdx.x*256 + threadIdx.x;
  if(i < ne) atomicAdd(&cnt[dst[i]], 1);
}

__global__ void k_dis(const int* __restrict__ cnt, float* __restrict__ dis, int n){
  int i = blockIdx.x*256 + threadIdx.x;
  if(i < n) dis[i] = rsqrtf((float)cnt[i] + 1.0f);
}

template<int NC>
__global__ void k_gcn_init(const float* __restrict__ h, const float* __restrict__ dis,
                           const float* __restrict__ b, float* __restrict__ agg, int n){
  int i = blockIdx.x*256 + threadIdx.x;
  if(i < n*NC){
    int r = i / NC, c = i % NC;
    float d = dis[r];
    agg[i] = fmaf(h[i], d*d, b[c]);
  }
}

template<int NC>
__global__ void k_gcn_scatter(const float* __restrict__ h, const float* __restrict__ dis,
                              const int* __restrict__ src, const int* __restrict__ dst,
                              int ne, float* __restrict__ agg){
  int gid = blockIdx.x*256 + threadIdx.x;
  int e = gid / NC, j = gid % NC;
  if(e >= ne) return;
  int s = src[e], d = dst[e];
  atomicAdd(&agg[d*NC + j], h[s*NC + j] * dis[s] * dis[d]);
}

__global__ void k_dp_scatter(const float* __restrict__ xp2, const int* __restrict__ src,
                             const int* __restrict__ dst, float* __restrict__ dpsum,
                             int* __restrict__ dpcnt){
  int gid = blockIdx.x*256 + threadIdx.x;
  int e = gid >> 4, j = gid & 15;
  if(e >= EDP) return;
  int s = src[e], d = dst[e] - NPROT;
  atomicAdd(&dpsum[d*16 + j], xp2[s*16 + j]);
  if(j == 0) atomicAdd(&dpcnt[d], 1);
}

__global__ void k_hier(const float* __restrict__ dpsum, const int* __restrict__ dpcnt,
                       const float* __restrict__ hg, float* __restrict__ xd){
  int gid = blockIdx.x*256 + threadIdx.x;
  int d = gid >> 4, j = gid & 15;
  if(d >= NDRUG) return;
  float inv = 1.0f / fmaxf((float)dpcnt[d], 1.0f);
  float acc = 0.f;
  #pragma unroll
  for(int k = 0; k < 16; k++) acc = fmaf(dpsum[d*16 + k] * inv, hg[k*16 + j], acc);
  xd[d*64 + 48 + j] = acc;
}

__global__ void k_embed(const float* __restrict__ xdrug, const float* __restrict__ embed,
                        float* __restrict__ xd){
  __shared__ float xs[64][65];
  __shared__ float es[64][48];
  int tid = threadIdx.x;
  int r = tid & 63;
  int cg = tid >> 6;
  int row0 = blockIdx.x * 64;
  int k0c = blockIdx.y * 512;
  float acc[12];
  #pragma unroll
  for(int j = 0; j < 12; j++) acc[j] = 0.f;
  for(int kt = 0; kt < 512; kt += 64){
    int k0 = k0c + kt;
    if(k0 >= INDRUG) break;
    __syncthreads();
    #pragma unroll
    for(int i = 0; i < 4; i++){
      int lin = tid + i*256;
      int rr = lin >> 4, kc = lin & 15;
      int grow = row0 + rr, gk = k0 + kc*4;
      float4 v = make_float4(0.f,0.f,0.f,0.f);
      if(grow < NDRUG && gk + 3 < INDRUG)
        v = *(const float4*)&xdrug[(size_t)grow * INDRUG + gk];
      xs[rr][kc*4+0]=v.x; xs[rr][kc*4+1]=v.y; xs[rr][kc*4+2]=v.z; xs[rr][kc*4+3]=v.w;
    }
    #pragma unroll
    for(int i = 0; i < 3; i++){
      int lin = tid + i*256;
      int kk = lin / 12, jc = lin % 12;
      float4 v = make_float4(0.f,0.f,0.f,0.f);
      if(k0 + kk < INDRUG)
        v = *(const float4*)&embed[(size_t)(k0 + kk) * NEMBED + jc*4];
      *(float4*)&es[kk][jc*4] = v;
    }
    __syncthreads();
    #pragma unroll 8
    for(int kk = 0; kk < 64; kk++){
      float xv = xs[r][kk];
      const float4* ep = (const float4*)&es[kk][cg*12];
      float4 e0 = ep[0], e1 = ep[1], e2 = ep[2];
      acc[0]=fmaf(xv,e0.x,acc[0]);  acc[1]=fmaf(xv,e0.y,acc[1]);
      acc[2]=fmaf(xv,e0.z,acc[2]);  acc[3]=fmaf(xv,e0.w,acc[3]);
      acc[4]=fmaf(xv,e1.x,acc[4]);  acc[5]=fmaf(xv,e1.y,acc[5]);
      acc[6]=fmaf(xv,e1.z,acc[6]);  acc[7]=fmaf(xv,e1.w,acc[7]);
      acc[8]=fmaf(xv,e2.x,acc[8]);  acc[9]=fmaf(xv,e2.y,acc[9]);
      acc[10]=fmaf(xv,e2.z,acc[10]); acc[11]=fmaf(xv,e2.w,acc[11]);
    }
  }
  int grow = row0 + r;
  if(grow < NDRUG){
    #pragma unroll
    for(int j = 0; j < 12; j++)
      atomicAdd(&xd[grow*64 + cg*12 + j], acc[j]);
  }
}

__global__ void k_embed_fin(float* __restrict__ xd, const float* __restrict__ dnorm){
  int gid = blockIdx.x*256 + threadIdx.x;
  if(gid >= NDRUG*48) return;
  int d = gid / 48, j = gid % 48;
  xd[d*64 + j] = xd[d*64 + j] / dnorm[d];
}

__global__ void k_rgcn1(const float* __restrict__ xd, const int* __restrict__ src,
                        const int* __restrict__ dst, const int* __restrict__ et,
                        const float* __restrict__ wet, float* __restrict__ rsum){
  int tid = threadIdx.x;
  int e = blockIdx.x*64 + (tid >> 2);
  if(e >= EDD) return;
  int jg = tid & 3;
  int s = src[e], d = dst[e], t = et[e];
  const float* x = xd + s*64;
  const float* w = wet + t*2048 + jg*8;
  float acc[8] = {0,0,0,0,0,0,0,0};
  #pragma unroll 8
  for(int i = 0; i < 64; i++){
    float xv = x[i];
    const float4* wp = (const float4*)(w + i*32);
    float4 w0 = wp[0], w1 = wp[1];
    acc[0]=fmaf(xv,w0.x,acc[0]); acc[1]=fmaf(xv,w0.y,acc[1]);
    acc[2]=fmaf(xv,w0.z,acc[2]); acc[3]=fmaf(xv,w0.w,acc[3]);
    acc[4]=fmaf(xv,w1.x,acc[4]); acc[5]=fmaf(xv,w1.y,acc[5]);
    acc[6]=fmaf(xv,w1.z,acc[6]); acc[7]=fmaf(xv,w1.w,acc[7]);
  }
  float* outp = rsum + d*32 + jg*8;
  #pragma unroll
  for(int j = 0; j < 8; j++) atomicAdd(&outp[j], acc[j]);
}

__global__ void k_rgcn2(const float* __restrict__ xd1, const int* __restrict__ src,
                        const int* __restrict__ dst, const int* __restrict__ et,
                        const float* __restrict__ wet, float* __restrict__ rsum){
  int tid = threadIdx.x;
  int e = blockIdx.x*128 + (tid >> 1);
  if(e >= EDD) return;
  int jg = tid & 1;
  int s = src[e], d = dst[e], t = et[e];
  const float* x = xd1 + s*32;
  const float* w = wet + t*512 + jg*8;
  float acc[8] = {0,0,0,0,0,0,0,0};
  #pragma unroll 8
  for(int i = 0; i < 32; i++){
    float xv = x[i];
    const float4* wp = (const float4*)(w + i*16);
    float4 w0 = wp[0], w1 = wp[1];
    acc[0]=fmaf(xv,w0.x,acc[0]); acc[1]=fmaf(xv,w0.y,acc[1]);
    acc[2]=fmaf(xv,w0.z,acc[2]); acc[3]=fmaf(xv,w0.w,acc[3]);
    acc[4]=fmaf(xv,w1.x,acc[4]); acc[5]=fmaf(xv,w1.y,acc[5]);
    acc[6]=fmaf(xv,w1.z,acc[6]); acc[7]=fmaf(xv,w1.w,acc[7]);
  }
  float* outp = rsum + d*16 + jg*8;
  #pragma unroll
  for(int j = 0; j < 8; j++) atomicAdd(&outp[j], acc[j]);
}

__global__ void k_root1(const float* __restrict__ rsum, const int* __restrict__ cnt,
                        const float* __restrict__ xd, const float* __restrict__ root,
                        float* __restrict__ xd1){
  int gid = blockIdx.x*256 + threadIdx.x;
  int d = gid >> 5, j = gid & 31;
  if(d >= NDRUG) return;
  float inv = 1.0f / fmaxf((float)cnt[d], 1.0f);
  float acc = rsum[d*32 + j] * inv;
  #pragma unroll
  for(int i = 0; i < 64; i++) acc = fmaf(xd[d*64 + i], root[i*32 + j], acc);
  xd1[d*32 + j] = fmaxf(acc, 0.f);
}

__global__ void k_root2(const float* __restrict__ rsum, const int* __restrict__ cnt,
                        const float* __restrict__ xd1, const float* __restrict__ root,
                        float* __restrict__ out){
  int gid = blockIdx.x*256 + threadIdx.x;
  int d = gid >> 4, j = gid & 15;
  if(d >= NDRUG) return;
  float inv = 1.0f / fmaxf((float)cnt[d], 1.0f);
  float acc = rsum[d*16 + j] * inv;
  #pragma unroll
  for(int i = 0; i < 32; i++) acc = fmaf(xd1[d*32 + i], root[i*16 + j], acc);
  out[d*16 + j] = acc;
}

// ======================= launch =======================

extern "C" void kernel_launch(void* const* d_in, const int* in_sizes, int n_in,
                              void* d_out, int out_size, void* d_ws, size_t ws_size,
                              hipStream_t stream){
  const float* x_drug  = (const float*)d_in[0];
  const float* d_norm  = (const float*)d_in[1];
  const float* x_prot  = (const float*)d_in[2];
  const int*   pp_ei   = (const int*)d_in[3];
  const int*   dp_ei   = (const int*)d_in[4];
  const int*   dd_ei   = (const int*)d_in[6];
  const int*   dd_et   = (const int*)d_in[7];
  const float* embed   = (const float*)d_in[9];
  const float* W1      = (const float*)d_in[10];
  const float* b1      = (const float*)d_in[11];
  const float* W2      = (const float*)d_in[12];
  const float* b2      = (const float*)d_in[13];
  const float* hgw     = (const float*)d_in[14];
  const float* att1    = (const float*)d_in[15];
  const float* basis1  = (const float*)d_in[16];
  const float* root1   = (const float*)d_in[17];
  const float* att2    = (const float*)d_in[18];
  const float* basis2  = (const float*)d_in[19];
  const float* root2   = (const float*)d_in[20];
  float* out = (float*)d_out;
  float* ws = (float*)d_ws;

  const int* pp_src = pp_ei;
  const int* pp_dst = pp_ei + EPP;
  const int* dp_src = dp_ei;
  const int* dp_dst = dp_ei + EDP;
  const int* dd_src = dd_ei;
  const int* dd_dst = dd_ei + EDD;

  // ---- fast-path ws layout ----
  auto pad = [](size_t n){ return (n + 15) & ~(size_t)15; };
  size_t o = 0;
  size_t oPPOFF = o; o += pad(NPROT + 1);
  size_t oDPOFF = o; o += pad(NDRUG + 1);
  size_t oDDOFF = o; o += pad(NDRUG + 1);
  size_t oDIS   = o; o += pad(NPROT);
  size_t oH1    = o; o += pad((size_t)NPROT*32);
  size_t oAGG1  = o; o += pad((size_t)NPROT*32);
  size_t oH2    = o; o += pad((size_t)NPROT*16);
  size_t oAGG2  = o; o += pad((size_t)NPROT*16);
  size_t oXD    = o; o += pad((size_t)NDRUG*64);
  size_t oXD1   = o; o += pad((size_t)NDRUG*32);
  size_t oWET1  = o; o += pad((size_t)NET*2048);
  size_t oWET2  = o; o += pad((size_t)NET*512);
  size_t oSRCPP = o; o += pad(EPP);
  size_t oSRCDP = o; o += pad(EDP);
  size_t oPOSDD = o; o += pad(EDD);
  size_t oCNT   = o; o += pad(NPROT);
  size_t oGH    = o; o += pad((size_t)NBLK*NPROT);
  size_t oXDP   = o; o += pad((size_t)8*NDRUG*48);
  size_t oMSGS  = o; o += pad((size_t)EDD*32);
  size_t need_bytes = o * 4;

  if(ws_size >= need_bytes){
    // =================== FAST PATH ===================
    int* ppoff = (int*)(ws + oPPOFF);
    int* dpoff = (int*)(ws + oDPOFF);
    int* ddoff = (int*)(ws + oDDOFF);
    float* dis = ws + oDIS;
    float* h1  = ws + oH1;
    float* agg1= ws + oAGG1;
    float* h2  = ws + oH2;
    float* agg2= ws + oAGG2;
    float* xd  = ws + oXD;
    float* xd1 = ws + oXD1;
    float* wet1= ws + oWET1;
    float* wet2= ws + oWET2;
    int* srcpp = (int*)(ws + oSRCPP);
    int* srcdp = (int*)(ws + oSRCDP);
    int* posdd = (int*)(ws + oPOSDD);
    int* cnt   = (int*)(ws + oCNT);
    int* gh    = (int*)(ws + oGH);
    float* xdp = ws + oXDP;
    float* msgs= ws + oMSGS;

    // ---- PP CSR (20000 bins, two 10000-bin passes) ----
    k_hist<10000><<<NBLK,256,0,stream>>>(pp_dst, EPP, 0, 0,     gh, NPROT);
    k_hist<10000><<<NBLK,256,0,stream>>>(pp_dst, EPP, 0, 10000, gh, NPROT);
    k_scan_bins<<<(NPROT+255)/256,256,0,stream>>>(gh, cnt, NPROT);
    k_scan_off<<<1,1024,0,stream>>>(cnt, ppoff, NPROT);
    k_scatter<10000,0><<<NBLK,256,0,stream>>>(pp_dst, pp_src, EPP, 0, 0,     gh, ppoff, NPROT, srcpp);
    k_scatter<10000,0><<<NBLK,256,0,stream>>>(pp_dst, pp_src, EPP, 0, 10000, gh, ppoff, NPROT, srcpp);
    k_dis_off<<<(NPROT+255)/256,256,0,stream>>>(ppoff, dis, NPROT);

    // ---- PP GCN layer 1 ----
    k_gemm<64,32,false><<<(NPROT*32+255)/256,256,0,stream>>>(x_prot, W1, h1, NPROT);
    k_gcn_gather<32><<<(NPROT+3)/4,256,0,stream>>>(h1, dis, ppoff, srcpp, b1, agg1, NPROT);
    // ---- PP GCN layer 2 ----
    k_gemm<32,16,true><<<(NPROT*16+255)/256,256,0,stream>>>(agg1, W2, h2, NPROT);
    k_gcn_gather<16><<<(NPROT+3)/4,256,0,stream>>>(h2, dis, ppoff, srcpp, b2, agg2, NPROT);

    // ---- DP CSR + hierarchy ----
    k_hist<4000><<<NBLK,256,0,stream>>>(dp_dst, EDP, NPROT, 0, gh, NDRUG);
    k_scan_bins<<<(NDRUG+255)/256,256,0,stream>>>(gh, cnt, NDRUG);
    k_scan_off<<<1,1024,0,stream>>>(cnt, dpoff, NDRUG);
    k_scatter<4000,0><<<NBLK,256,0,stream>>>(dp_dst, dp_src, EDP, NPROT, 0, gh, dpoff, NDRUG, srcdp);
    k_dp_gather<<<(NDRUG+3)/4,256,0,stream>>>(agg2, dpoff, srcdp, hgw, xd);

    // ---- drug embedding ----
    {
      dim3 g((NDRUG+63)/64, 8);
      k_embed_p<<<g,256,0,stream>>>(x_drug, embed, xdp);
    }
    k_embed_fin2<<<(NDRUG*48+255)/256,256,0,stream>>>(xdp, d_norm, xd);

    // ---- RGCN prep ----
    k_wet<<<(NET*2048+255)/256,256,0,stream>>>(att1, basis1, wet1, 2048);
    k_wet<<<(NET*512+255)/256,256,0,stream>>>(att2, basis2, wet2, 512);
    k_hist<4000><<<NBLK,256,0,stream>>>(dd_dst, EDD, 0, 0, gh, NDRUG);
    k_scan_bins<<<(NDRUG+255)/256,256,0,stream>>>(gh, cnt, NDRUG);
    k_scan_off<<<1,1024,0,stream>>>(cnt, ddoff, NDRUG);
    k_scatter<4000,1><<<NBLK,256,0,stream>>>(dd_dst, dd_src, EDD, 0, 0, gh, ddoff, NDRUG, posdd);

    // ---- RGCN layer 1 ----
    k_rgcn1_msgs<<<EDD/64,256,0,stream>>>(xd, dd_src, dd_et, posdd, wet1, msgs);
    k_rgcn1_reduce<<<(NDRUG+3)/4,256,0,stream>>>(msgs, ddoff, xd, root1, xd1);
    // ---- RGCN layer 2 ----
    k_rgcn2_msgs<<<(EDD+127)/128,256,0,stream>>>(xd1, dd_src, dd_et, posdd, wet2, msgs);
    k_rgcn2_reduce<<<(NDRUG+3)/4,256,0,stream>>>(msgs, ddoff, xd1, root2, out);
  } else {
    // =================== FALLBACK (round-1, atomic) ===================
    int*   cnt_pp = (int*)(ws + O_CNTPP);
    float* dis    = ws + O_DIS;
    float* h1     = ws + O_H1;
    float* agg1   = ws + O_AGG1;
    float* h2     = ws + O_H2;
    float* agg2   = ws + O_AGG2;
    float* dpsum  = ws + O_DPSUM;
    int*   dpcnt  = (int*)(ws + O_DPCNT);
    float* xd     = ws + O_XD;
    float* wet1   = ws + O_WET1;
    float* wet2   = ws + O_WET2;
    int*   cntdd  = (int*)(ws + O_CNTDD);
    float* rsum1  = ws + O_RSUM1;
    float* xd1    = ws + O_XD1;
    float* rsum2  = ws + O_RSUM2;

    hipMemsetAsync(cnt_pp, 0, NPROT*sizeof(int), stream);
    hipMemsetAsync(dpsum,  0, (64000 + 4000)*sizeof(float), stream);
    hipMemsetAsync(xd,     0, NDRUG*64*sizeof(float), stream);
    hipMemsetAsync(cntdd,  0, NDRUG*sizeof(int), stream);
    hipMemsetAsync(rsum1,  0, NDRUG*32*sizeof(float), stream);
    hipMemsetAsync(rsum2,  0, NDRUG*16*sizeof(float), stream);

    k_count_int<<<(EPP+255)/256,256,0,stream>>>(pp_dst, EPP, cnt_pp);
    k_dis<<<(NPROT+255)/256,256,0,stream>>>(cnt_pp, dis, NPROT);
    k_gemm<64,32,false><<<(NPROT*32+255)/256,256,0,stream>>>(x_prot, W1, h1, NPROT);
    k_gcn_init<32><<<(NPROT*32+255)/256,256,0,stream>>>(h1, dis, b1, agg1, NPROT);
    k_gcn_scatter<32><<<(EPP*32)/256,256,0,stream>>>(h1, dis, pp_src, pp_dst, EPP, agg1);
    k_gemm<32,16,true><<<(NPROT*16+255)/256,256,0,stream>>>(agg1, W2, h2, NPROT);
    k_gcn_init<16><<<(NPROT*16+255)/256,256,0,stream>>>(h2, dis, b2, agg2, NPROT);
    k_gcn_scatter<16><<<(EPP*16)/256,256,0,stream>>>(h2, dis, pp_src, pp_dst, EPP, agg2);
    k_dp_scatter<<<(EDP*16)/256,256,0,stream>>>(agg2, dp_src, dp_dst, dpsum, dpcnt);
    k_hier<<<(NDRUG*16+255)/256,256,0,stream>>>(dpsum, dpcnt, hgw, xd);
    {
      dim3 g((NDRUG+63)/64, 8);
      k_embed<<<g,256,0,stream>>>(x_drug, embed, xd);
    }
    k_embed_fin<<<(NDRUG*48+255)/256,256,0,stream>>>(xd, d_norm);
    k_wet<<<(NET*2048+255)/256,256,0,stream>>>(att1, basis1, wet1, 2048);
    k_wet<<<(NET*512+255)/256,256,0,stream>>>(att2, basis2, wet2, 512);
    k_count_int<<<(EDD+255)/256,256,0,stream>>>(dd_dst, EDD, cntdd);
    k_rgcn1<<<EDD/64,256,0,stream>>>(xd, dd_src, dd_dst, dd_et, wet1, rsum1);
    k_root1<<<(NDRUG*32+255)/256,256,0,stream>>>(rsum1, cntdd, xd, root1, xd1);
    k_rgcn2<<<(EDD+127)/128,256,0,stream>>>(xd1, dd_src, dd_dst, dd_et, wet2, rsum2);
    k_root2<<<(NDRUG*16+255)/256,256,0,stream>>>(rsum2, cntdd, xd1, root2, out);
  }
}